// Round 4
// baseline (905.805 us; speedup 1.0000x reference)
//
#include <hip/hip_runtime.h>
#include <math.h>

// ---------------- graph build (CSR by dst) ----------------

__global__ void k_init(int* counts, int* cursor, int n) {
  int i = blockIdx.x * blockDim.x + threadIdx.x;
  if (i < n) { counts[i] = 0; cursor[i] = 0; }
}

__global__ void k_hist(const int* __restrict__ dst, int E, int* counts) {
  int e = blockIdx.x * blockDim.x + threadIdx.x;
  if (e < E) atomicAdd(&counts[dst[e]], 1);
}

// per-256-chunk inclusive scan -> chunk-local exclusive + chunk totals
__global__ void k_scan_chunks(const int* __restrict__ counts, int n,
                              int* __restrict__ chunk_ex, int* __restrict__ partials) {
  __shared__ int s[256];
  int tid = threadIdx.x;
  int i = blockIdx.x * 256 + tid;
  int v = (i < n) ? counts[i] : 0;
  s[tid] = v;
  __syncthreads();
  for (int off = 1; off < 256; off <<= 1) {
    int t = (tid >= off) ? s[tid - off] : 0;
    __syncthreads();
    s[tid] += t;
    __syncthreads();
  }
  if (i < n) chunk_ex[i] = s[tid] - v;
  if (tid == 255) partials[blockIdx.x] = s[255];
}

// single-block exclusive scan of chunk totals (np <= 1024)
__global__ void k_scan_partials(int* partials, int np) {
  __shared__ int s[1024];
  int tid = threadIdx.x;
  int v = (tid < np) ? partials[tid] : 0;
  s[tid] = v;
  __syncthreads();
  for (int off = 1; off < 1024; off <<= 1) {
    int t = (tid >= off) ? s[tid - off] : 0;
    __syncthreads();
    s[tid] += t;
    __syncthreads();
  }
  if (tid < np) partials[tid] = s[tid] - v;
}

__global__ void k_finalize(const int* __restrict__ counts, const int* __restrict__ chunk_ex,
                           const int* __restrict__ partials, int n, int E,
                           int* __restrict__ row_start, float* __restrict__ dinv) {
  int i = blockIdx.x * blockDim.x + threadIdx.x;
  if (i < n) {
    row_start[i] = chunk_ex[i] + partials[i >> 8];
    dinv[i] = rsqrtf((float)(counts[i] + 1));  // +1 = self-loop
  }
  if (i == 0) row_start[n] = E;
}

__global__ void k_fill(const int* __restrict__ src, const int* __restrict__ dst,
                       int E, const int* __restrict__ row_start, int* cursor,
                       int* __restrict__ col) {
  int e = blockIdx.x * blockDim.x + threadIdx.x;
  if (e < E) {
    int d = dst[e];
    int pos = row_start[d] + atomicAdd(&cursor[d], 1);
    col[pos] = src[e];
  }
}

// ---------------- GEMM1: h1[n,128] = x[n,512] @ W1[512,128] ----------------
// BM=64, BN=128, BK=32; 256 thr; per-thread 8 rows x 4 cols.
__global__ __launch_bounds__(256) void k_gemm1(
    const float* __restrict__ x, const float* __restrict__ W,
    float* __restrict__ h, int n) {
  __shared__ float As[64][36];   // +4 pad keeps float4 stores 16B-aligned
  __shared__ float Bs[32][128];
  int tid = threadIdx.x;
  int bm = blockIdx.x * 64;
  int c0 = (tid & 31) * 4, r0 = (tid >> 5) * 8;
  float acc[8][4] = {};
  for (int k0 = 0; k0 < 512; k0 += 32) {
#pragma unroll
    for (int i = 0; i < 2; ++i) {           // A tile 64x32 = 512 float4
      int idx = tid + i * 256;
      int r = idx >> 3, kq = idx & 7;
      int rg = bm + r; if (rg >= n) rg = n - 1;   // clamp (tail block)
      *(float4*)&As[r][kq * 4] = *(const float4*)&x[rg * 512 + k0 + kq * 4];
    }
#pragma unroll
    for (int i = 0; i < 4; ++i) {           // B tile 32x128 = 1024 float4
      int idx = tid + i * 256;
      int r = idx >> 5, c4 = idx & 31;
      *(float4*)&Bs[r][c4 * 4] = *(const float4*)&W[(k0 + r) * 128 + c4 * 4];
    }
    __syncthreads();
#pragma unroll
    for (int kk = 0; kk < 32; ++kk) {
      float4 bb = *(const float4*)&Bs[kk][c0];
#pragma unroll
      for (int r = 0; r < 8; ++r) {
        float a = As[r0 + r][kk];
        acc[r][0] = fmaf(a, bb.x, acc[r][0]);
        acc[r][1] = fmaf(a, bb.y, acc[r][1]);
        acc[r][2] = fmaf(a, bb.z, acc[r][2]);
        acc[r][3] = fmaf(a, bb.w, acc[r][3]);
      }
    }
    __syncthreads();
  }
#pragma unroll
  for (int r = 0; r < 8; ++r) {
    int rg = bm + r0 + r;
    if (rg < n)
      *(float4*)&h[rg * 128 + c0] = make_float4(acc[r][0], acc[r][1], acc[r][2], acc[r][3]);
  }
}

// ---------------- GEMM2: h2[n,64] = h1a[n,128] @ W2[128,64] ----------------
__global__ __launch_bounds__(256) void k_gemm2(
    const float* __restrict__ a, const float* __restrict__ W,
    float* __restrict__ h, int n) {
  __shared__ float As[64][36];
  __shared__ float Bs[32][64];
  int tid = threadIdx.x;
  int bm = blockIdx.x * 64;
  int c0 = (tid & 15) * 4, r0 = (tid >> 4) * 4;
  float acc[4][4] = {};
  for (int k0 = 0; k0 < 128; k0 += 32) {
#pragma unroll
    for (int i = 0; i < 2; ++i) {           // A tile 64x32
      int idx = tid + i * 256;
      int r = idx >> 3, kq = idx & 7;
      int rg = bm + r; if (rg >= n) rg = n - 1;
      *(float4*)&As[r][kq * 4] = *(const float4*)&a[rg * 128 + k0 + kq * 4];
    }
#pragma unroll
    for (int i = 0; i < 2; ++i) {           // B tile 32x64 = 512 float4
      int idx = tid + i * 256;
      int r = idx >> 4, c4 = idx & 15;
      *(float4*)&Bs[r][c4 * 4] = *(const float4*)&W[(k0 + r) * 64 + c4 * 4];
    }
    __syncthreads();
#pragma unroll
    for (int kk = 0; kk < 32; ++kk) {
      float4 bb = *(const float4*)&Bs[kk][c0];
#pragma unroll
      for (int r = 0; r < 4; ++r) {
        float av = As[r0 + r][kk];
        acc[r][0] = fmaf(av, bb.x, acc[r][0]);
        acc[r][1] = fmaf(av, bb.y, acc[r][1]);
        acc[r][2] = fmaf(av, bb.z, acc[r][2]);
        acc[r][3] = fmaf(av, bb.w, acc[r][3]);
      }
    }
    __syncthreads();
  }
#pragma unroll
  for (int r = 0; r < 4; ++r) {
    int rg = bm + r0 + r;
    if (rg < n)
      *(float4*)&h[rg * 64 + c0] = make_float4(acc[r][0], acc[r][1], acc[r][2], acc[r][3]);
  }
}

// -------- agg layer1: one wave per node, lane = 2 feature dims (float2) ----
// out = relu(dinv[i]*(sum_e dinv[s]*h1[s] + dinv[i]*h1[i]) + b1)
__global__ __launch_bounds__(256) void k_agg1(
    const float* __restrict__ h1, const int* __restrict__ row_start,
    const int* __restrict__ col, const float* __restrict__ dinv,
    const float* __restrict__ b1, float* __restrict__ h1a, int n) {
  int wid = (blockIdx.x * blockDim.x + threadIdx.x) >> 6;
  int lane = threadIdx.x & 63;
  if (wid >= n) return;
  const float2* hv = (const float2*)h1;
  int beg = row_start[wid], end = row_start[wid + 1];
  float di = dinv[wid];
  float ax = 0.f, ay = 0.f;
  for (int j = beg; j < end; ++j) {
    int s = col[j];                      // wave-uniform -> HW broadcast
    float wgt = dinv[s];
    float2 v = hv[s * 64 + lane];        // coalesced 512B row read
    ax = fmaf(wgt, v.x, ax);
    ay = fmaf(wgt, v.y, ay);
  }
  float2 vs = hv[wid * 64 + lane];       // self-loop
  ax = fmaf(di, vs.x, ax);
  ay = fmaf(di, vs.y, ay);
  float2 bb = ((const float2*)b1)[lane];
  float ox = fmaf(di, ax, bb.x);
  float oy = fmaf(di, ay, bb.y);
  ((float2*)h1a)[wid * 64 + lane] = make_float2(fmaxf(ox, 0.f), fmaxf(oy, 0.f));
}

// -------- agg layer2 + bias + log_softmax: one wave per node, lane = col ---
__global__ __launch_bounds__(256) void k_agg2(
    const float* __restrict__ h2, const int* __restrict__ row_start,
    const int* __restrict__ col, const float* __restrict__ dinv,
    const float* __restrict__ b2, float* __restrict__ out, int n) {
  int wid = (blockIdx.x * blockDim.x + threadIdx.x) >> 6;
  int lane = threadIdx.x & 63;
  if (wid >= n) return;
  int beg = row_start[wid], end = row_start[wid + 1];
  float di = dinv[wid];
  float acc = 0.f;
  for (int j = beg; j < end; ++j) {
    int s = col[j];
    acc = fmaf(dinv[s], h2[s * 64 + lane], acc);
  }
  acc = fmaf(di, h2[wid * 64 + lane], acc);
  float v = fmaf(di, acc, b2[lane]);
  // log_softmax across the 64 lanes (= 64 output cols)
  float m = v;
#pragma unroll
  for (int off = 32; off > 0; off >>= 1) m = fmaxf(m, __shfl_xor(m, off));
  float e = expf(v - m);
  float ssum = e;
#pragma unroll
  for (int off = 32; off > 0; off >>= 1) ssum += __shfl_xor(ssum, off);
  out[wid * 64 + lane] = (v - m) - logf(ssum);
}

// ---------------- launch ----------------

extern "C" void kernel_launch(void* const* d_in, const int* in_sizes, int n_in,
                              void* d_out, int out_size, void* d_ws, size_t ws_size,
                              hipStream_t stream) {
  const float* x   = (const float*)d_in[0];
  const int*   ei  = (const int*)d_in[1];     // int32 per harness convention
  const float* W1  = (const float*)d_in[2];
  const float* b1  = (const float*)d_in[3];
  const float* W2  = (const float*)d_in[4];
  const float* b2  = (const float*)d_in[5];
  float* out = (float*)d_out;
  const int n = in_sizes[0] / 512;
  const int E = in_sizes[1] / 2;
  const int* src = ei;
  const int* dst = ei + E;

  char* w = (char*)d_ws;
  auto alloc = [&](size_t bytes) -> char* {
    char* p = w; w += (bytes + 255) & ~(size_t)255; return p;
  };
  // persistent across the whole pipeline
  int*   row_start = (int*)alloc(((size_t)n + 1) * 4);
  float* dinv      = (float*)alloc((size_t)n * 4);
  int*   col       = (int*)alloc((size_t)E * 4);
  float* h1        = (float*)alloc((size_t)n * 128 * 4);
  float* h1a       = (float*)alloc((size_t)n * 128 * 4);
  float* h2        = h1;   // h1 dead after k_agg1 -> reuse
  // graph-build temporaries: dead before k_gemm1 writes h1 -> alias into h1
  int* counts   = (int*)h1;
  int* cursor   = counts + n;
  int* chunk_ex = cursor + n;
  int* partials = chunk_ex + n;   // 1024 ints, still << n*128

  const int nch = (n + 255) / 256;   // 391 for n=100000 (<=1024)

  hipLaunchKernelGGL(k_init,          dim3((n + 255) / 256), dim3(256), 0, stream, counts, cursor, n);
  hipLaunchKernelGGL(k_hist,          dim3((E + 255) / 256), dim3(256), 0, stream, dst, E, counts);
  hipLaunchKernelGGL(k_scan_chunks,   dim3(nch),             dim3(256), 0, stream, counts, n, chunk_ex, partials);
  hipLaunchKernelGGL(k_scan_partials, dim3(1),               dim3(1024), 0, stream, partials, nch);
  hipLaunchKernelGGL(k_finalize,      dim3((n + 255) / 256), dim3(256), 0, stream, counts, chunk_ex, partials, n, E, row_start, dinv);
  hipLaunchKernelGGL(k_fill,          dim3((E + 255) / 256), dim3(256), 0, stream, src, dst, E, row_start, cursor, col);
  hipLaunchKernelGGL(k_gemm1,         dim3((n + 63) / 64),   dim3(256), 0, stream, x, W1, h1, n);
  hipLaunchKernelGGL(k_agg1,          dim3((n + 3) / 4),     dim3(256), 0, stream, h1, row_start, col, dinv, b1, h1a, n);
  hipLaunchKernelGGL(k_gemm2,         dim3((n + 63) / 64),   dim3(256), 0, stream, h1a, W2, h2, n);
  hipLaunchKernelGGL(k_agg2,          dim3((n + 3) / 4),     dim3(256), 0, stream, h2, row_start, col, dinv, b2, out, n);
}

// Round 5
// 808.451 us; speedup vs baseline: 1.1204x; 1.1204x over previous
//
#include <hip/hip_runtime.h>
#include <math.h>

typedef unsigned short u16;
typedef __attribute__((ext_vector_type(8))) short bf16x8;
typedef __attribute__((ext_vector_type(4))) float f32x4;

__device__ inline u16 f2bf(float v) {            // RNE f32->bf16
  union { float f; unsigned u; } x; x.f = v;
  unsigned r = x.u + 0x7fff + ((x.u >> 16) & 1);
  return (u16)(r >> 16);
}
__device__ inline float bf2f(u16 b) {
  union { unsigned u; float f; } x; x.u = ((unsigned)b) << 16; return x.f;
}

// ---------------- graph build (CSR by dst) ----------------

__global__ void k_hist(const int* __restrict__ dst, int E, int* counts) {
  int e = blockIdx.x * blockDim.x + threadIdx.x;
  if (e < E) atomicAdd(&counts[dst[e]], 1);
}

__global__ void k_scan_chunks(const int* __restrict__ counts, int n,
                              int* __restrict__ chunk_ex, int* __restrict__ partials) {
  __shared__ int s[256];
  int tid = threadIdx.x;
  int i = blockIdx.x * 256 + tid;
  int v = (i < n) ? counts[i] : 0;
  s[tid] = v;
  __syncthreads();
  for (int off = 1; off < 256; off <<= 1) {
    int t = (tid >= off) ? s[tid - off] : 0;
    __syncthreads();
    s[tid] += t;
    __syncthreads();
  }
  if (i < n) chunk_ex[i] = s[tid] - v;
  if (tid == 255) partials[blockIdx.x] = s[255];
}

__global__ void k_scan_partials(int* partials, int np) {
  __shared__ int s[1024];
  int tid = threadIdx.x;
  int v = (tid < np) ? partials[tid] : 0;
  s[tid] = v;
  __syncthreads();
  for (int off = 1; off < 1024; off <<= 1) {
    int t = (tid >= off) ? s[tid - off] : 0;
    __syncthreads();
    s[tid] += t;
    __syncthreads();
  }
  if (tid < np) partials[tid] = s[tid] - v;
}

__global__ void k_finalize(const int* __restrict__ counts, const int* __restrict__ chunk_ex,
                           const int* __restrict__ partials, int n, int E,
                           int* __restrict__ row_start, float* __restrict__ dinv) {
  int i = blockIdx.x * blockDim.x + threadIdx.x;
  if (i < n) {
    row_start[i] = chunk_ex[i] + partials[i >> 8];
    dinv[i] = rsqrtf((float)(counts[i] + 1));  // +1 = self-loop
  }
  if (i == 0) row_start[n] = E;
}

// fill packed edge payload: (src, dinv[src]) per CSR slot
__global__ void k_fill(const int* __restrict__ src, const int* __restrict__ dst,
                       int E, const int* __restrict__ row_start, int* cursor,
                       const float* __restrict__ dinv, int2* __restrict__ pk) {
  int e = blockIdx.x * blockDim.x + threadIdx.x;
  if (e < E) {
    int d = dst[e], s = src[e];
    int pos = row_start[d] + atomicAdd(&cursor[d], 1);
    pk[pos] = make_int2(s, __float_as_int(dinv[s]));
  }
}

// ---------------- W preprocess: f32 [K][N] -> hi/lo bf16 transposed [N][K] --
template<int LOGN>
__global__ void k_wprep(const float* __restrict__ W, u16* __restrict__ hi,
                        u16* __restrict__ lo, int total, int K) {
  int i = blockIdx.x * 256 + threadIdx.x;
  if (i >= total) return;
  int k = i >> LOGN, nn = i & ((1 << LOGN) - 1);
  float v = W[i];
  u16 h = f2bf(v);
  hi[(size_t)nn * K + k] = h;
  lo[(size_t)nn * K + k] = f2bf(v - bf2f(h));
}

// ---------------- split-bf16 MFMA GEMM: C[M,N] = A[M,K] @ B[K,N] ----------
// A f32 row-major; B pre-split hi/lo bf16, N-major [N][K].
// x = x_hi + x_lo; C ~= Ah*Bh + Al*Bh + Ah*Bl (err ~2^-18 rel, f32-class).
// BM=64, BK=64, 256 thr = 4 waves (WM x WN grid), full-N block tile.
template<int N, int K, int WM, int WN>
__global__ __launch_bounds__(256) void k_gemm_mfma(
    const float* __restrict__ A, const u16* __restrict__ Bt_hi,
    const u16* __restrict__ Bt_lo, float* __restrict__ C, int M) {
  constexpr int MW = 64 / WM;      // wave m-tile
  constexpr int NW = N / WN;       // wave n-tile (=64)
  constexpr int MFRAG = MW / 16, NFRAG = NW / 16;
  constexpr int LDP = 72;          // lds pitch in bf16 elems (144B: 2-way-free banks)
  __shared__ u16 As_hi[64][LDP], As_lo[64][LDP];
  __shared__ u16 Bs_hi[N][LDP],  Bs_lo[N][LDP];
  int tid = threadIdx.x;
  int wave = tid >> 6, lane = tid & 63;
  int wm = wave / WN, wn = wave % WN;
  int m0 = wm * MW, n0 = wn * NW;
  int bm = blockIdx.x * 64;
  int lr = lane & 15, lk = (lane >> 4) * 8;
  f32x4 acc[MFRAG][NFRAG] = {};
  for (int k0 = 0; k0 < K; k0 += 64) {
    // stage A: 64 rows x 64 k, f32 -> hi/lo bf16
#pragma unroll
    for (int p = 0; p < 4; ++p) {
      int r = (tid >> 4) + p * 16;
      int kc = tid & 15;
      int rg = bm + r; if (rg >= M) rg = M - 1;          // tail clamp
      float4 v = *(const float4*)&A[(size_t)rg * K + k0 + kc * 4];
      u16 h0 = f2bf(v.x), h1 = f2bf(v.y), h2 = f2bf(v.z), h3 = f2bf(v.w);
      u16 l0 = f2bf(v.x - bf2f(h0)), l1 = f2bf(v.y - bf2f(h1));
      u16 l2 = f2bf(v.z - bf2f(h2)), l3 = f2bf(v.w - bf2f(h3));
      uint2 hh, ll;
      hh.x = (unsigned)h0 | ((unsigned)h1 << 16);
      hh.y = (unsigned)h2 | ((unsigned)h3 << 16);
      ll.x = (unsigned)l0 | ((unsigned)l1 << 16);
      ll.y = (unsigned)l2 | ((unsigned)l3 << 16);
      *(uint2*)&As_hi[r][kc * 4] = hh;
      *(uint2*)&As_lo[r][kc * 4] = ll;
    }
    // stage B: N rows x 64 k bf16 (16B chunks)
#pragma unroll
    for (int p = 0; p < N / 32; ++p) {
      int nr = (tid >> 3) + p * 32;
      int ch = tid & 7;
      *(uint4*)&Bs_hi[nr][ch * 8] = *(const uint4*)&Bt_hi[(size_t)nr * K + k0 + ch * 8];
      *(uint4*)&Bs_lo[nr][ch * 8] = *(const uint4*)&Bt_lo[(size_t)nr * K + k0 + ch * 8];
    }
    __syncthreads();
#pragma unroll
    for (int ks = 0; ks < 2; ++ks) {
      int kb = ks * 32 + lk;
      bf16x8 a_h[MFRAG], a_l[MFRAG], b_h[NFRAG], b_l[NFRAG];
#pragma unroll
      for (int mf = 0; mf < MFRAG; ++mf) {
        a_h[mf] = *(const bf16x8*)&As_hi[m0 + mf * 16 + lr][kb];
        a_l[mf] = *(const bf16x8*)&As_lo[m0 + mf * 16 + lr][kb];
      }
#pragma unroll
      for (int nf = 0; nf < NFRAG; ++nf) {
        b_h[nf] = *(const bf16x8*)&Bs_hi[n0 + nf * 16 + lr][kb];
        b_l[nf] = *(const bf16x8*)&Bs_lo[n0 + nf * 16 + lr][kb];
      }
#pragma unroll
      for (int mf = 0; mf < MFRAG; ++mf)
#pragma unroll
        for (int nf = 0; nf < NFRAG; ++nf) {
          acc[mf][nf] = __builtin_amdgcn_mfma_f32_16x16x32_bf16(a_h[mf], b_h[nf], acc[mf][nf], 0, 0, 0);
          acc[mf][nf] = __builtin_amdgcn_mfma_f32_16x16x32_bf16(a_l[mf], b_h[nf], acc[mf][nf], 0, 0, 0);
          acc[mf][nf] = __builtin_amdgcn_mfma_f32_16x16x32_bf16(a_h[mf], b_l[nf], acc[mf][nf], 0, 0, 0);
        }
    }
    __syncthreads();
  }
  // epilogue: C/D layout col=lane&15, row=(lane>>4)*4+i  [verified m89/m91]
#pragma unroll
  for (int mf = 0; mf < MFRAG; ++mf)
#pragma unroll
    for (int nf = 0; nf < NFRAG; ++nf)
#pragma unroll
      for (int i = 0; i < 4; ++i) {
        int row = bm + m0 + mf * 16 + (lane >> 4) * 4 + i;
        int col = n0 + nf * 16 + lr;
        if (row < M) C[(size_t)row * N + col] = acc[mf][nf][i];
      }
}

// -------- agg layer1: one wave per node, lane = 2 feature dims (float2) ----
__global__ __launch_bounds__(256) void k_agg1(
    const float* __restrict__ h1, const int* __restrict__ row_start,
    const int2* __restrict__ pk, const float* __restrict__ dinv,
    const float* __restrict__ b1, float* __restrict__ h1a, int n) {
  int wid = (blockIdx.x * blockDim.x + threadIdx.x) >> 6;
  int lane = threadIdx.x & 63;
  if (wid >= n) return;
  const float2* hv = (const float2*)h1;
  int beg = row_start[wid], end = row_start[wid + 1];
  float di = dinv[wid];
  float ax = 0.f, ay = 0.f;
  for (int j = beg; j < end; ++j) {
    int2 p = pk[j];                      // wave-uniform 8B -> broadcast
    float wgt = __int_as_float(p.y);
    float2 v = hv[(size_t)p.x * 64 + lane];
    ax = fmaf(wgt, v.x, ax);
    ay = fmaf(wgt, v.y, ay);
  }
  float2 vs = hv[(size_t)wid * 64 + lane];   // self-loop
  ax = fmaf(di, vs.x, ax);
  ay = fmaf(di, vs.y, ay);
  float2 bb = ((const float2*)b1)[lane];
  float ox = fmaf(di, ax, bb.x);
  float oy = fmaf(di, ay, bb.y);
  ((float2*)h1a)[(size_t)wid * 64 + lane] = make_float2(fmaxf(ox, 0.f), fmaxf(oy, 0.f));
}

// -------- agg layer2 + bias + log_softmax: one wave per node, lane = col ---
__global__ __launch_bounds__(256) void k_agg2(
    const float* __restrict__ h2, const int* __restrict__ row_start,
    const int2* __restrict__ pk, const float* __restrict__ dinv,
    const float* __restrict__ b2, float* __restrict__ out, int n) {
  int wid = (blockIdx.x * blockDim.x + threadIdx.x) >> 6;
  int lane = threadIdx.x & 63;
  if (wid >= n) return;
  int beg = row_start[wid], end = row_start[wid + 1];
  float di = dinv[wid];
  float acc = 0.f;
  for (int j = beg; j < end; ++j) {
    int2 p = pk[j];
    acc = fmaf(__int_as_float(p.y), h2[(size_t)p.x * 64 + lane], acc);
  }
  acc = fmaf(di, h2[(size_t)wid * 64 + lane], acc);
  float v = fmaf(di, acc, b2[lane]);
  float m = v;
#pragma unroll
  for (int off = 32; off > 0; off >>= 1) m = fmaxf(m, __shfl_xor(m, off));
  float e = expf(v - m);
  float ssum = e;
#pragma unroll
  for (int off = 32; off > 0; off >>= 1) ssum += __shfl_xor(ssum, off);
  out[(size_t)wid * 64 + lane] = (v - m) - logf(ssum);
}

// ---------------- launch ----------------

extern "C" void kernel_launch(void* const* d_in, const int* in_sizes, int n_in,
                              void* d_out, int out_size, void* d_ws, size_t ws_size,
                              hipStream_t stream) {
  const float* x   = (const float*)d_in[0];
  const int*   ei  = (const int*)d_in[1];
  const float* W1  = (const float*)d_in[2];
  const float* b1  = (const float*)d_in[3];
  const float* W2  = (const float*)d_in[4];
  const float* b2  = (const float*)d_in[5];
  float* out = (float*)d_out;
  const int n = in_sizes[0] / 512;
  const int E = in_sizes[1] / 2;
  const int* src = ei;
  const int* dst = ei + E;

  char* w = (char*)d_ws;
  auto alloc = [&](size_t bytes) -> char* {
    char* p = w; w += (bytes + 255) & ~(size_t)255; return p;
  };
  // persistent
  int*   row_start = (int*)alloc(((size_t)n + 1) * 4);
  float* dinv      = (float*)alloc((size_t)n * 4);
  int2*  pk        = (int2*)alloc((size_t)E * 8);
  u16*   wt1_hi    = (u16*)alloc(512 * 128 * 2);
  u16*   wt1_lo    = (u16*)alloc(512 * 128 * 2);
  u16*   wt2_hi    = (u16*)alloc(128 * 64 * 2);
  u16*   wt2_lo    = (u16*)alloc(128 * 64 * 2);
  float* h1        = (float*)alloc((size_t)n * 128 * 4);
  float* h1a       = (float*)alloc((size_t)n * 128 * 4);
  float* h2        = h1;   // h1 dead after k_agg1 -> reuse
  // graph-build temporaries alias h1 (dead before k_gemm writes h1)
  int* counts   = (int*)h1;
  int* cursor   = counts + n;
  int* chunk_ex = cursor + n;
  int* partials = chunk_ex + n;   // 1024 ints

  const int nch = (n + 255) / 256;   // 391 for n=100000 (<=1024)

  hipMemsetAsync(counts, 0, (size_t)2 * n * 4, stream);   // counts + cursor
  hipLaunchKernelGGL((k_wprep<7>), dim3(512 * 128 / 256), dim3(256), 0, stream, W1, wt1_hi, wt1_lo, 512 * 128, 512);
  hipLaunchKernelGGL((k_wprep<6>), dim3(128 * 64 / 256),  dim3(256), 0, stream, W2, wt2_hi, wt2_lo, 128 * 64, 128);
  hipLaunchKernelGGL(k_hist,          dim3((E + 255) / 256), dim3(256), 0, stream, dst, E, counts);
  hipLaunchKernelGGL(k_scan_chunks,   dim3(nch),             dim3(256), 0, stream, counts, n, chunk_ex, partials);
  hipLaunchKernelGGL(k_scan_partials, dim3(1),               dim3(1024), 0, stream, partials, nch);
  hipLaunchKernelGGL(k_finalize,      dim3((n + 255) / 256), dim3(256), 0, stream, counts, chunk_ex, partials, n, E, row_start, dinv);
  hipLaunchKernelGGL(k_fill,          dim3((E + 255) / 256), dim3(256), 0, stream, src, dst, E, row_start, cursor, dinv, pk);
  hipLaunchKernelGGL((k_gemm_mfma<128, 512, 2, 2>), dim3((n + 63) / 64), dim3(256), 0, stream, x, wt1_hi, wt1_lo, h1, n);
  hipLaunchKernelGGL(k_agg1,          dim3((n + 3) / 4),     dim3(256), 0, stream, h1, row_start, pk, dinv, b1, h1a, n);
  hipLaunchKernelGGL((k_gemm_mfma<64, 128, 4, 1>),  dim3((n + 63) / 64), dim3(256), 0, stream, h1a, wt2_hi, wt2_lo, h2, n);
  hipLaunchKernelGGL(k_agg2,          dim3((n + 3) / 4),     dim3(256), 0, stream, h2, row_start, pk, dinv, b2, out, n);
}

// Round 6
// 629.811 us; speedup vs baseline: 1.4382x; 1.2836x over previous
//
#include <hip/hip_runtime.h>
#include <math.h>

typedef unsigned short u16;
typedef unsigned int u32;
typedef __attribute__((ext_vector_type(8))) short bf16x8;
typedef __attribute__((ext_vector_type(4))) float f32x4;

__device__ inline u16 f2bf(float v) {            // RNE f32->bf16
  union { float f; unsigned u; } x; x.f = v;
  unsigned r = x.u + 0x7fff + ((x.u >> 16) & 1);
  return (u16)(r >> 16);
}
__device__ inline float bf2f(u16 b) {
  union { unsigned u; float f; } x; x.u = ((unsigned)b) << 16; return x.f;
}
__device__ inline float bflo(u32 v) { return __uint_as_float(v << 16); }
__device__ inline float bfhi(u32 v) { return __uint_as_float(v & 0xffff0000u); }

// ---------------- graph build (CSR by dst) ----------------

__global__ void k_hist(const int* __restrict__ dst, int E, int* counts) {
  int e = blockIdx.x * blockDim.x + threadIdx.x;
  if (e < E) atomicAdd(&counts[dst[e]], 1);
}

__global__ void k_scan_chunks(const int* __restrict__ counts, int n,
                              int* __restrict__ chunk_ex, int* __restrict__ partials) {
  __shared__ int s[256];
  int tid = threadIdx.x;
  int i = blockIdx.x * 256 + tid;
  int v = (i < n) ? counts[i] : 0;
  s[tid] = v;
  __syncthreads();
  for (int off = 1; off < 256; off <<= 1) {
    int t = (tid >= off) ? s[tid - off] : 0;
    __syncthreads();
    s[tid] += t;
    __syncthreads();
  }
  if (i < n) chunk_ex[i] = s[tid] - v;
  if (tid == 255) partials[blockIdx.x] = s[255];
}

__global__ void k_scan_partials(int* partials, int np) {
  __shared__ int s[1024];
  int tid = threadIdx.x;
  int v = (tid < np) ? partials[tid] : 0;
  s[tid] = v;
  __syncthreads();
  for (int off = 1; off < 1024; off <<= 1) {
    int t = (tid >= off) ? s[tid - off] : 0;
    __syncthreads();
    s[tid] += t;
    __syncthreads();
  }
  if (tid < np) partials[tid] = s[tid] - v;
}

__global__ void k_finalize(const int* __restrict__ counts, const int* __restrict__ chunk_ex,
                           const int* __restrict__ partials, int n, int E,
                           int* __restrict__ row_start, float* __restrict__ dinv) {
  int i = blockIdx.x * blockDim.x + threadIdx.x;
  if (i < n) {
    row_start[i] = chunk_ex[i] + partials[i >> 8];
    dinv[i] = rsqrtf((float)(counts[i] + 1));  // +1 = self-loop
  }
  if (i == 0) row_start[n] = E;
}

// fill packed edge payload: (src, dinv[src]) per CSR slot
__global__ void k_fill(const int* __restrict__ src, const int* __restrict__ dst,
                       int E, const int* __restrict__ row_start, int* cursor,
                       const float* __restrict__ dinv, int2* __restrict__ pk) {
  int e = blockIdx.x * blockDim.x + threadIdx.x;
  if (e < E) {
    int d = dst[e], s = src[e];
    int pos = row_start[d] + atomicAdd(&cursor[d], 1);
    pk[pos] = make_int2(s, __float_as_int(dinv[s]));
  }
}

// ---------------- W preprocess: f32 [K][N] -> hi/lo bf16 transposed [N][K] --
template<int LOGN>
__global__ void k_wprep(const float* __restrict__ W, u16* __restrict__ hi,
                        u16* __restrict__ lo, int total, int K) {
  int i = blockIdx.x * 256 + threadIdx.x;
  if (i >= total) return;
  int k = i >> LOGN, nn = i & ((1 << LOGN) - 1);
  float v = W[i];
  u16 h = f2bf(v);
  hi[(size_t)nn * K + k] = h;
  lo[(size_t)nn * K + k] = f2bf(v - bf2f(h));
}

// ---------------- split-bf16 MFMA GEMM: C[M,N] = A[M,K] @ B[K,N] ----------
// A f32 row-major; B pre-split hi/lo bf16, N-major [N][K]; C written as bf16.
// x = x_hi + x_lo; C ~= Ah*Bh + Al*Bh + Ah*Bl (err ~2^-18 rel, f32-class).
template<int N, int K, int WM, int WN>
__global__ __launch_bounds__(256) void k_gemm_mfma(
    const float* __restrict__ A, const u16* __restrict__ Bt_hi,
    const u16* __restrict__ Bt_lo, u16* __restrict__ C, int M) {
  constexpr int MW = 64 / WM;      // wave m-tile
  constexpr int NW = N / WN;       // wave n-tile (=64)
  constexpr int MFRAG = MW / 16, NFRAG = NW / 16;
  constexpr int LDP = 72;          // lds pitch in bf16 elems
  __shared__ u16 As_hi[64][LDP], As_lo[64][LDP];
  __shared__ u16 Bs_hi[N][LDP],  Bs_lo[N][LDP];
  int tid = threadIdx.x;
  int wave = tid >> 6, lane = tid & 63;
  int wm = wave / WN, wn = wave % WN;
  int m0 = wm * MW, n0 = wn * NW;
  int bm = blockIdx.x * 64;
  int lr = lane & 15, lk = (lane >> 4) * 8;
  f32x4 acc[MFRAG][NFRAG] = {};
  for (int k0 = 0; k0 < K; k0 += 64) {
#pragma unroll
    for (int p = 0; p < 4; ++p) {           // stage A 64x64 f32 -> hi/lo
      int r = (tid >> 4) + p * 16;
      int kc = tid & 15;
      int rg = bm + r; if (rg >= M) rg = M - 1;
      float4 v = *(const float4*)&A[(size_t)rg * K + k0 + kc * 4];
      u16 h0 = f2bf(v.x), h1 = f2bf(v.y), h2 = f2bf(v.z), h3 = f2bf(v.w);
      u16 l0 = f2bf(v.x - bf2f(h0)), l1 = f2bf(v.y - bf2f(h1));
      u16 l2 = f2bf(v.z - bf2f(h2)), l3 = f2bf(v.w - bf2f(h3));
      uint2 hh, ll;
      hh.x = (unsigned)h0 | ((unsigned)h1 << 16);
      hh.y = (unsigned)h2 | ((unsigned)h3 << 16);
      ll.x = (unsigned)l0 | ((unsigned)l1 << 16);
      ll.y = (unsigned)l2 | ((unsigned)l3 << 16);
      *(uint2*)&As_hi[r][kc * 4] = hh;
      *(uint2*)&As_lo[r][kc * 4] = ll;
    }
#pragma unroll
    for (int p = 0; p < N / 32; ++p) {      // stage B Nx64 bf16
      int nr = (tid >> 3) + p * 32;
      int ch = tid & 7;
      *(uint4*)&Bs_hi[nr][ch * 8] = *(const uint4*)&Bt_hi[(size_t)nr * K + k0 + ch * 8];
      *(uint4*)&Bs_lo[nr][ch * 8] = *(const uint4*)&Bt_lo[(size_t)nr * K + k0 + ch * 8];
    }
    __syncthreads();
#pragma unroll
    for (int ks = 0; ks < 2; ++ks) {
      int kb = ks * 32 + lk;
      bf16x8 a_h[MFRAG], a_l[MFRAG], b_h[NFRAG], b_l[NFRAG];
#pragma unroll
      for (int mf = 0; mf < MFRAG; ++mf) {
        a_h[mf] = *(const bf16x8*)&As_hi[m0 + mf * 16 + lr][kb];
        a_l[mf] = *(const bf16x8*)&As_lo[m0 + mf * 16 + lr][kb];
      }
#pragma unroll
      for (int nf = 0; nf < NFRAG; ++nf) {
        b_h[nf] = *(const bf16x8*)&Bs_hi[n0 + nf * 16 + lr][kb];
        b_l[nf] = *(const bf16x8*)&Bs_lo[n0 + nf * 16 + lr][kb];
      }
#pragma unroll
      for (int mf = 0; mf < MFRAG; ++mf)
#pragma unroll
        for (int nf = 0; nf < NFRAG; ++nf) {
          acc[mf][nf] = __builtin_amdgcn_mfma_f32_16x16x32_bf16(a_h[mf], b_h[nf], acc[mf][nf], 0, 0, 0);
          acc[mf][nf] = __builtin_amdgcn_mfma_f32_16x16x32_bf16(a_l[mf], b_h[nf], acc[mf][nf], 0, 0, 0);
          acc[mf][nf] = __builtin_amdgcn_mfma_f32_16x16x32_bf16(a_h[mf], b_l[nf], acc[mf][nf], 0, 0, 0);
        }
    }
    __syncthreads();
  }
  // epilogue: C/D layout col=lane&15, row=(lane>>4)*4+i -> bf16 store
#pragma unroll
  for (int mf = 0; mf < MFRAG; ++mf)
#pragma unroll
    for (int nf = 0; nf < NFRAG; ++nf)
#pragma unroll
      for (int i = 0; i < 4; ++i) {
        int row = bm + m0 + mf * 16 + (lane >> 4) * 4 + i;
        int col = n0 + nf * 16 + lr;
        if (row < M) C[(size_t)row * N + col] = f2bf(acc[mf][nf][i]);
      }
}

// -------- agg layer1: wave/node, lane = 2 dims (u32 = 2 bf16), 4-way MLP ---
__global__ __launch_bounds__(256) void k_agg1(
    const u16* __restrict__ h1, const int* __restrict__ row_start,
    const int2* __restrict__ pk, const float* __restrict__ dinv,
    const float* __restrict__ b1, float* __restrict__ h1a, int n) {
  int wid = (blockIdx.x * blockDim.x + threadIdx.x) >> 6;
  int lane = threadIdx.x & 63;
  if (wid >= n) return;
  const u32* hv = (const u32*)h1;          // row = 64 u32
  int beg = row_start[wid], end = row_start[wid + 1];
  float di = dinv[wid];
  float ax = 0.f, ay = 0.f;
  int j = beg;
  for (; j + 4 <= end; j += 4) {           // 4 independent row loads in flight
    int2 p0 = pk[j], p1 = pk[j + 1], p2 = pk[j + 2], p3 = pk[j + 3];
    u32 v0 = hv[(size_t)p0.x * 64 + lane];
    u32 v1 = hv[(size_t)p1.x * 64 + lane];
    u32 v2 = hv[(size_t)p2.x * 64 + lane];
    u32 v3 = hv[(size_t)p3.x * 64 + lane];
    float w0 = __int_as_float(p0.y), w1 = __int_as_float(p1.y);
    float w2 = __int_as_float(p2.y), w3 = __int_as_float(p3.y);
    ax = fmaf(w0, bflo(v0), ax); ay = fmaf(w0, bfhi(v0), ay);
    ax = fmaf(w1, bflo(v1), ax); ay = fmaf(w1, bfhi(v1), ay);
    ax = fmaf(w2, bflo(v2), ax); ay = fmaf(w2, bfhi(v2), ay);
    ax = fmaf(w3, bflo(v3), ax); ay = fmaf(w3, bfhi(v3), ay);
  }
  for (; j < end; ++j) {
    int2 p = pk[j];
    u32 v = hv[(size_t)p.x * 64 + lane];
    float wgt = __int_as_float(p.y);
    ax = fmaf(wgt, bflo(v), ax); ay = fmaf(wgt, bfhi(v), ay);
  }
  u32 vs = hv[(size_t)wid * 64 + lane];    // self-loop
  ax = fmaf(di, bflo(vs), ax);
  ay = fmaf(di, bfhi(vs), ay);
  float2 bb = ((const float2*)b1)[lane];
  float ox = fmaf(di, ax, bb.x);
  float oy = fmaf(di, ay, bb.y);
  ((float2*)h1a)[(size_t)wid * 64 + lane] = make_float2(fmaxf(ox, 0.f), fmaxf(oy, 0.f));
}

// -------- agg layer2 + bias + log_softmax: wave/node, lane = col, 4-way MLP -
__global__ __launch_bounds__(256) void k_agg2(
    const u16* __restrict__ h2, const int* __restrict__ row_start,
    const int2* __restrict__ pk, const float* __restrict__ dinv,
    const float* __restrict__ b2, float* __restrict__ out, int n) {
  int wid = (blockIdx.x * blockDim.x + threadIdx.x) >> 6;
  int lane = threadIdx.x & 63;
  if (wid >= n) return;
  int beg = row_start[wid], end = row_start[wid + 1];
  float di = dinv[wid];
  float acc = 0.f;
  int j = beg;
  for (; j + 4 <= end; j += 4) {
    int2 p0 = pk[j], p1 = pk[j + 1], p2 = pk[j + 2], p3 = pk[j + 3];
    u16 v0 = h2[(size_t)p0.x * 64 + lane];
    u16 v1 = h2[(size_t)p1.x * 64 + lane];
    u16 v2 = h2[(size_t)p2.x * 64 + lane];
    u16 v3 = h2[(size_t)p3.x * 64 + lane];
    acc = fmaf(__int_as_float(p0.y), bf2f(v0), acc);
    acc = fmaf(__int_as_float(p1.y), bf2f(v1), acc);
    acc = fmaf(__int_as_float(p2.y), bf2f(v2), acc);
    acc = fmaf(__int_as_float(p3.y), bf2f(v3), acc);
  }
  for (; j < end; ++j) {
    int2 p = pk[j];
    acc = fmaf(__int_as_float(p.y), bf2f(h2[(size_t)p.x * 64 + lane]), acc);
  }
  acc = fmaf(di, bf2f(h2[(size_t)wid * 64 + lane]), acc);
  float v = fmaf(di, acc, b2[lane]);
  float m = v;
#pragma unroll
  for (int off = 32; off > 0; off >>= 1) m = fmaxf(m, __shfl_xor(m, off));
  float e = expf(v - m);
  float ssum = e;
#pragma unroll
  for (int off = 32; off > 0; off >>= 1) ssum += __shfl_xor(ssum, off);
  out[(size_t)wid * 64 + lane] = (v - m) - logf(ssum);
}

// ---------------- launch ----------------

extern "C" void kernel_launch(void* const* d_in, const int* in_sizes, int n_in,
                              void* d_out, int out_size, void* d_ws, size_t ws_size,
                              hipStream_t stream) {
  const float* x   = (const float*)d_in[0];
  const int*   ei  = (const int*)d_in[1];
  const float* W1  = (const float*)d_in[2];
  const float* b1  = (const float*)d_in[3];
  const float* W2  = (const float*)d_in[4];
  const float* b2  = (const float*)d_in[5];
  float* out = (float*)d_out;
  const int n = in_sizes[0] / 512;
  const int E = in_sizes[1] / 2;
  const int* src = ei;
  const int* dst = ei + E;

  char* w = (char*)d_ws;
  auto alloc = [&](size_t bytes) -> char* {
    char* p = w; w += (bytes + 255) & ~(size_t)255; return p;
  };
  // persistent
  int*   row_start = (int*)alloc(((size_t)n + 1) * 4);
  float* dinv      = (float*)alloc((size_t)n * 4);
  int2*  pk        = (int2*)alloc((size_t)E * 8);
  u16*   wt1_hi    = (u16*)alloc(512 * 128 * 2);
  u16*   wt1_lo    = (u16*)alloc(512 * 128 * 2);
  u16*   wt2_hi    = (u16*)alloc(128 * 64 * 2);
  u16*   wt2_lo    = (u16*)alloc(128 * 64 * 2);
  u16*   h1        = (u16*)alloc((size_t)n * 128 * 2);   // bf16 activations
  float* h1a       = (float*)alloc((size_t)n * 128 * 4); // f32 (GEMM2 input)
  u16*   h2        = h1;   // h1 dead after k_agg1 -> reuse for bf16 h2
  // graph-build temporaries alias h1 (dead before k_gemm writes h1)
  int* counts   = (int*)h1;
  int* cursor   = counts + n;
  int* chunk_ex = cursor + n;
  int* partials = chunk_ex + n;   // 1024 ints

  const int nch = (n + 255) / 256;   // 391 for n=100000 (<=1024)

  hipMemsetAsync(counts, 0, (size_t)2 * n * 4, stream);   // counts + cursor
  hipLaunchKernelGGL((k_wprep<7>), dim3(512 * 128 / 256), dim3(256), 0, stream, W1, wt1_hi, wt1_lo, 512 * 128, 512);
  hipLaunchKernelGGL((k_wprep<6>), dim3(128 * 64 / 256),  dim3(256), 0, stream, W2, wt2_hi, wt2_lo, 128 * 64, 128);
  hipLaunchKernelGGL(k_hist,          dim3((E + 255) / 256), dim3(256), 0, stream, dst, E, counts);
  hipLaunchKernelGGL(k_scan_chunks,   dim3(nch),             dim3(256), 0, stream, counts, n, chunk_ex, partials);
  hipLaunchKernelGGL(k_scan_partials, dim3(1),               dim3(1024), 0, stream, partials, nch);
  hipLaunchKernelGGL(k_finalize,      dim3((n + 255) / 256), dim3(256), 0, stream, counts, chunk_ex, partials, n, E, row_start, dinv);
  hipLaunchKernelGGL(k_fill,          dim3((E + 255) / 256), dim3(256), 0, stream, src, dst, E, row_start, cursor, dinv, pk);
  hipLaunchKernelGGL((k_gemm_mfma<128, 512, 2, 2>), dim3((n + 63) / 64), dim3(256), 0, stream, x, wt1_hi, wt1_lo, h1, n);
  hipLaunchKernelGGL(k_agg1,          dim3((n + 3) / 4),     dim3(256), 0, stream, h1, row_start, pk, dinv, b1, h1a, n);
  hipLaunchKernelGGL((k_gemm_mfma<64, 128, 4, 1>),  dim3((n + 63) / 64), dim3(256), 0, stream, h1a, wt2_hi, wt2_lo, h2, n);
  hipLaunchKernelGGL(k_agg2,          dim3((n + 3) / 4),     dim3(256), 0, stream, h2, row_start, pk, dinv, b2, out, n);
}

// Round 8
// 622.820 us; speedup vs baseline: 1.4544x; 1.0112x over previous
//
#include <hip/hip_runtime.h>
#include <math.h>

typedef unsigned short u16;
typedef unsigned int u32;
typedef __attribute__((ext_vector_type(8))) short bf16x8;
typedef __attribute__((ext_vector_type(4))) float f32x4;

__device__ inline u16 f2bf(float v) {            // RNE f32->bf16
  union { float f; unsigned u; } x; x.f = v;
  unsigned r = x.u + 0x7fff + ((x.u >> 16) & 1);
  return (u16)(r >> 16);
}
__device__ inline float bf2f(u16 b) {
  union { unsigned u; float f; } x; x.u = ((unsigned)b) << 16; return x.f;
}
__device__ inline float bflo(u32 v) { return __uint_as_float(v << 16); }
__device__ inline float bfhi(u32 v) { return __uint_as_float(v & 0xffff0000u); }

// ---------------- graph build (CSR by dst) ----------------

__global__ void k_hist(const int* __restrict__ dst, int E, int* counts) {
  int e = blockIdx.x * blockDim.x + threadIdx.x;
  if (e < E) atomicAdd(&counts[dst[e]], 1);
}

__global__ void k_scan_chunks(const int* __restrict__ counts, int n,
                              int* __restrict__ chunk_ex, int* __restrict__ partials) {
  __shared__ int s[256];
  int tid = threadIdx.x;
  int i = blockIdx.x * 256 + tid;
  int v = (i < n) ? counts[i] : 0;
  s[tid] = v;
  __syncthreads();
  for (int off = 1; off < 256; off <<= 1) {
    int t = (tid >= off) ? s[tid - off] : 0;
    __syncthreads();
    s[tid] += t;
    __syncthreads();
  }
  if (i < n) chunk_ex[i] = s[tid] - v;
  if (tid == 255) partials[blockIdx.x] = s[255];
}

// finalize with inline partials-prefix: block b reduces partials[0..b-1]
__global__ void k_finalize(const int* __restrict__ counts, const int* __restrict__ chunk_ex,
                           const int* __restrict__ partials, int n, int E,
                           int* __restrict__ row_start, float* __restrict__ dinv) {
  int cb = blockIdx.x, tid = threadIdx.x;
  int a = 0;
  for (int c = tid; c < cb; c += 256) a += partials[c];
#pragma unroll
  for (int off = 32; off > 0; off >>= 1) a += __shfl_down(a, off);
  __shared__ int wsum[4];
  if ((tid & 63) == 0) wsum[tid >> 6] = a;
  __syncthreads();
  int base = wsum[0] + wsum[1] + wsum[2] + wsum[3];
  int i = cb * 256 + tid;
  if (i < n) {
    row_start[i] = chunk_ex[i] + base;
    dinv[i] = rsqrtf((float)(counts[i] + 1));  // +1 = self-loop
  }
  if (cb == 0 && tid == 0) row_start[n] = E;
}

// fill packed edge payload: (src, dinv[src]) per CSR slot
__global__ void k_fill(const int* __restrict__ src, const int* __restrict__ dst,
                       int E, const int* __restrict__ row_start, int* cursor,
                       const float* __restrict__ dinv, int2* __restrict__ pk) {
  int e = blockIdx.x * blockDim.x + threadIdx.x;
  if (e < E) {
    int d = dst[e], s = src[e];
    int pos = row_start[d] + atomicAdd(&cursor[d], 1);
    pk[pos] = make_int2(s, __float_as_int(dinv[s]));
  }
}

// -------- W preprocess (both weights, one launch): f32 [K][N] -> hi/lo [N][K]
__global__ void k_wprep(const float* __restrict__ W1, const float* __restrict__ W2,
                        u16* __restrict__ hi1, u16* __restrict__ lo1,
                        u16* __restrict__ hi2, u16* __restrict__ lo2) {
  int i = blockIdx.x * 256 + threadIdx.x;
  if (i < 512 * 128) {
    int k = i >> 7, nn = i & 127;
    float v = W1[i];
    u16 h = f2bf(v);
    hi1[nn * 512 + k] = h;
    lo1[nn * 512 + k] = f2bf(v - bf2f(h));
  } else {
    int j = i - 512 * 128;
    int k = j >> 6, nn = j & 63;
    float v = W2[j];
    u16 h = f2bf(v);
    hi2[nn * 128 + k] = h;
    lo2[nn * 128 + k] = f2bf(v - bf2f(h));
  }
}

// ---------------- split-bf16 MFMA GEMM: C[M,N] = A[M,K] @ B[K,N] ----------
// AF32=true: A f32, split on the fly. AF32=false: A pre-split hi/lo bf16.
// B pre-split hi/lo bf16 N-major [N][K]. C written bf16.
// C ~= Ah*Bh + Al*Bh + Ah*Bl (err ~2^-18 rel, f32-class).
template<int BM, int N, int K, int WM, int WN, int TPB, bool AF32>
__global__ __launch_bounds__(TPB, 4) void k_gemm_mfma(
    const void* __restrict__ Aptr, const u16* __restrict__ Alo_ptr,
    const u16* __restrict__ Bt_hi, const u16* __restrict__ Bt_lo,
    u16* __restrict__ C, int M) {
  constexpr int MW = BM / WM, NW = N / WN;
  constexpr int MFRAG = MW / 16, NFRAG = NW / 16;
  constexpr int LDP = 72;
  __shared__ u16 As_hi[BM][LDP], As_lo[BM][LDP];
  __shared__ u16 Bs_hi[N][LDP],  Bs_lo[N][LDP];
  int tid = threadIdx.x;
  int wave = tid >> 6, lane = tid & 63;
  int wm = wave / WN, wn = wave % WN;
  int m0 = wm * MW, n0 = wn * NW;
  int bm = blockIdx.x * BM;
  int lr = lane & 15, lk = (lane >> 4) * 8;
  f32x4 acc[MFRAG][NFRAG] = {};
  for (int k0 = 0; k0 < K; k0 += 64) {
    if constexpr (AF32) {
      const float* A = (const float*)Aptr;
#pragma unroll
      for (int p = 0; p < BM * 16 / TPB; ++p) {
        int idx = tid + p * TPB;
        int r = idx >> 4, kc = idx & 15;
        int rg = bm + r; if (rg >= M) rg = M - 1;
        float4 v = *(const float4*)&A[(size_t)rg * K + k0 + kc * 4];
        u16 h0 = f2bf(v.x), h1 = f2bf(v.y), h2 = f2bf(v.z), h3 = f2bf(v.w);
        u16 l0 = f2bf(v.x - bf2f(h0)), l1 = f2bf(v.y - bf2f(h1));
        u16 l2 = f2bf(v.z - bf2f(h2)), l3 = f2bf(v.w - bf2f(h3));
        uint2 hh, ll;
        hh.x = (unsigned)h0 | ((unsigned)h1 << 16);
        hh.y = (unsigned)h2 | ((unsigned)h3 << 16);
        ll.x = (unsigned)l0 | ((unsigned)l1 << 16);
        ll.y = (unsigned)l2 | ((unsigned)l3 << 16);
        *(uint2*)&As_hi[r][kc * 4] = hh;
        *(uint2*)&As_lo[r][kc * 4] = ll;
      }
    } else {
      const u16* Ahi = (const u16*)Aptr;
#pragma unroll
      for (int p = 0; p < BM * 16 / TPB; ++p) {
        int idx = tid + p * TPB;
        int r = idx >> 4, kc = idx & 15;
        int rg = bm + r; if (rg >= M) rg = M - 1;
        *(uint2*)&As_hi[r][kc * 4] = *(const uint2*)&Ahi[(size_t)rg * K + k0 + kc * 4];
        *(uint2*)&As_lo[r][kc * 4] = *(const uint2*)&Alo_ptr[(size_t)rg * K + k0 + kc * 4];
      }
    }
#pragma unroll
    for (int p = 0; p < N * 8 / TPB; ++p) {
      int idx = tid + p * TPB;
      int nr = idx >> 3, ch = idx & 7;
      *(uint4*)&Bs_hi[nr][ch * 8] = *(const uint4*)&Bt_hi[(size_t)nr * K + k0 + ch * 8];
      *(uint4*)&Bs_lo[nr][ch * 8] = *(const uint4*)&Bt_lo[(size_t)nr * K + k0 + ch * 8];
    }
    __syncthreads();
#pragma unroll
    for (int ks = 0; ks < 2; ++ks) {
      int kb = ks * 32 + lk;
      bf16x8 a_h[MFRAG], a_l[MFRAG], b_h[NFRAG], b_l[NFRAG];
#pragma unroll
      for (int mf = 0; mf < MFRAG; ++mf) {
        a_h[mf] = *(const bf16x8*)&As_hi[m0 + mf * 16 + lr][kb];
        a_l[mf] = *(const bf16x8*)&As_lo[m0 + mf * 16 + lr][kb];
      }
#pragma unroll
      for (int nf = 0; nf < NFRAG; ++nf) {
        b_h[nf] = *(const bf16x8*)&Bs_hi[n0 + nf * 16 + lr][kb];
        b_l[nf] = *(const bf16x8*)&Bs_lo[n0 + nf * 16 + lr][kb];
      }
#pragma unroll
      for (int mf = 0; mf < MFRAG; ++mf)
#pragma unroll
        for (int nf = 0; nf < NFRAG; ++nf) {
          acc[mf][nf] = __builtin_amdgcn_mfma_f32_16x16x32_bf16(a_h[mf], b_h[nf], acc[mf][nf], 0, 0, 0);
          acc[mf][nf] = __builtin_amdgcn_mfma_f32_16x16x32_bf16(a_l[mf], b_h[nf], acc[mf][nf], 0, 0, 0);
          acc[mf][nf] = __builtin_amdgcn_mfma_f32_16x16x32_bf16(a_h[mf], b_l[nf], acc[mf][nf], 0, 0, 0);
        }
    }
    __syncthreads();
  }
  // epilogue: C/D layout col=lane&15, row=(lane>>4)*4+i -> bf16 store
#pragma unroll
  for (int mf = 0; mf < MFRAG; ++mf)
#pragma unroll
    for (int nf = 0; nf < NFRAG; ++nf)
#pragma unroll
      for (int i = 0; i < 4; ++i) {
        int row = bm + m0 + mf * 16 + (lane >> 4) * 4 + i;
        int col = n0 + nf * 16 + lr;
        if (row < M) C[(size_t)row * N + col] = f2bf(acc[mf][nf][i]);
      }
}

// -------- agg layer1: wave/node, lane = 2 dims, 4-way MLP; out pre-split ----
__global__ __launch_bounds__(256) void k_agg1(
    const u16* __restrict__ h1, const int* __restrict__ row_start,
    const int2* __restrict__ pk, const float* __restrict__ dinv,
    const float* __restrict__ b1, u16* __restrict__ ha_hi,
    u16* __restrict__ ha_lo, int n) {
  int wid = (blockIdx.x * blockDim.x + threadIdx.x) >> 6;
  int lane = threadIdx.x & 63;
  if (wid >= n) return;
  const u32* hv = (const u32*)h1;          // row = 64 u32
  int beg = row_start[wid], end = row_start[wid + 1];
  float di = dinv[wid];
  float ax = 0.f, ay = 0.f;
  int j = beg;
  for (; j + 4 <= end; j += 4) {           // 4 independent row loads in flight
    int2 p0 = pk[j], p1 = pk[j + 1], p2 = pk[j + 2], p3 = pk[j + 3];
    u32 v0 = hv[(size_t)p0.x * 64 + lane];
    u32 v1 = hv[(size_t)p1.x * 64 + lane];
    u32 v2 = hv[(size_t)p2.x * 64 + lane];
    u32 v3 = hv[(size_t)p3.x * 64 + lane];
    float w0 = __int_as_float(p0.y), w1 = __int_as_float(p1.y);
    float w2 = __int_as_float(p2.y), w3 = __int_as_float(p3.y);
    ax = fmaf(w0, bflo(v0), ax); ay = fmaf(w0, bfhi(v0), ay);
    ax = fmaf(w1, bflo(v1), ax); ay = fmaf(w1, bfhi(v1), ay);
    ax = fmaf(w2, bflo(v2), ax); ay = fmaf(w2, bfhi(v2), ay);
    ax = fmaf(w3, bflo(v3), ax); ay = fmaf(w3, bfhi(v3), ay);
  }
  for (; j < end; ++j) {
    int2 p = pk[j];
    u32 v = hv[(size_t)p.x * 64 + lane];
    float wgt = __int_as_float(p.y);
    ax = fmaf(wgt, bflo(v), ax); ay = fmaf(wgt, bfhi(v), ay);
  }
  u32 vs = hv[(size_t)wid * 64 + lane];    // self-loop
  ax = fmaf(di, bflo(vs), ax);
  ay = fmaf(di, bfhi(vs), ay);
  float2 bb = ((const float2*)b1)[lane];
  float ox = fmaxf(fmaf(di, ax, bb.x), 0.f);
  float oy = fmaxf(fmaf(di, ay, bb.y), 0.f);
  // pre-split for GEMM2's A operand (err 2^-17 rel vs f32)
  u16 hx = f2bf(ox), hy = f2bf(oy);
  u16 lx = f2bf(ox - bf2f(hx)), ly = f2bf(oy - bf2f(hy));
  ((u32*)ha_hi)[(size_t)wid * 64 + lane] = (u32)hx | ((u32)hy << 16);
  ((u32*)ha_lo)[(size_t)wid * 64 + lane] = (u32)lx | ((u32)ly << 16);
}

// -------- agg layer2 + bias + log_softmax: wave/node, lane = col, 4-way MLP -
__global__ __launch_bounds__(256) void k_agg2(
    const u16* __restrict__ h2, const int* __restrict__ row_start,
    const int2* __restrict__ pk, const float* __restrict__ dinv,
    const float* __restrict__ b2, float* __restrict__ out, int n) {
  int wid = (blockIdx.x * blockDim.x + threadIdx.x) >> 6;
  int lane = threadIdx.x & 63;
  if (wid >= n) return;
  int beg = row_start[wid], end = row_start[wid + 1];
  float di = dinv[wid];
  float acc = 0.f;
  int j = beg;
  for (; j + 4 <= end; j += 4) {
    int2 p0 = pk[j], p1 = pk[j + 1], p2 = pk[j + 2], p3 = pk[j + 3];
    u16 v0 = h2[(size_t)p0.x * 64 + lane];
    u16 v1 = h2[(size_t)p1.x * 64 + lane];
    u16 v2 = h2[(size_t)p2.x * 64 + lane];
    u16 v3 = h2[(size_t)p3.x * 64 + lane];
    acc = fmaf(__int_as_float(p0.y), bf2f(v0), acc);
    acc = fmaf(__int_as_float(p1.y), bf2f(v1), acc);
    acc = fmaf(__int_as_float(p2.y), bf2f(v2), acc);
    acc = fmaf(__int_as_float(p3.y), bf2f(v3), acc);
  }
  for (; j < end; ++j) {
    int2 p = pk[j];
    acc = fmaf(__int_as_float(p.y), bf2f(h2[(size_t)p.x * 64 + lane]), acc);
  }
  acc = fmaf(di, bf2f(h2[(size_t)wid * 64 + lane]), acc);
  float v = fmaf(di, acc, b2[lane]);
  float m = v;
#pragma unroll
  for (int off = 32; off > 0; off >>= 1) m = fmaxf(m, __shfl_xor(m, off));
  float e = expf(v - m);
  float ssum = e;
#pragma unroll
  for (int off = 32; off > 0; off >>= 1) ssum += __shfl_xor(ssum, off);
  out[(size_t)wid * 64 + lane] = (v - m) - logf(ssum);
}

// ---------------- launch ----------------

extern "C" void kernel_launch(void* const* d_in, const int* in_sizes, int n_in,
                              void* d_out, int out_size, void* d_ws, size_t ws_size,
                              hipStream_t stream) {
  const float* x   = (const float*)d_in[0];
  const int*   ei  = (const int*)d_in[1];
  const float* W1  = (const float*)d_in[2];
  const float* b1  = (const float*)d_in[3];
  const float* W2  = (const float*)d_in[4];
  const float* b2  = (const float*)d_in[5];
  float* out = (float*)d_out;
  const int n = in_sizes[0] / 512;
  const int E = in_sizes[1] / 2;
  const int* src = ei;
  const int* dst = ei + E;

  char* w = (char*)d_ws;
  auto alloc = [&](size_t bytes) -> char* {
    char* p = w; w += (bytes + 255) & ~(size_t)255; return p;
  };
  // persistent
  int*   row_start = (int*)alloc(((size_t)n + 1) * 4);
  float* dinv      = (float*)alloc((size_t)n * 4);
  int2*  pk        = (int2*)alloc((size_t)E * 8);
  u16*   wt1_hi    = (u16*)alloc(512 * 128 * 2);
  u16*   wt1_lo    = (u16*)alloc(512 * 128 * 2);
  u16*   wt2_hi    = (u16*)alloc(128 * 64 * 2);
  u16*   wt2_lo    = (u16*)alloc(128 * 64 * 2);
  u16*   h1        = (u16*)alloc((size_t)n * 128 * 2);   // bf16 activations
  u16*   ha_hi     = (u16*)alloc((size_t)n * 128 * 2);   // pre-split h1a
  u16*   ha_lo     = (u16*)alloc((size_t)n * 128 * 2);
  u16*   h2        = h1;   // h1 dead after k_agg1 -> reuse for bf16 h2
  // graph-build temporaries alias h1 (dead before gemm1 writes h1)
  int* counts   = (int*)h1;
  int* cursor   = counts + n;
  int* chunk_ex = cursor + n;
  int* partials = chunk_ex + n;   // 1024 ints

  const int nch = (n + 255) / 256;   // 391 for n=100000

  hipMemsetAsync(counts, 0, (size_t)2 * n * 4, stream);   // counts + cursor
  hipLaunchKernelGGL(k_wprep, dim3((512 * 128 + 128 * 64) / 256), dim3(256), 0, stream,
                     W1, W2, wt1_hi, wt1_lo, wt2_hi, wt2_lo);
  hipLaunchKernelGGL(k_hist,        dim3((E + 255) / 256), dim3(256), 0, stream, dst, E, counts);
  hipLaunchKernelGGL(k_scan_chunks, dim3(nch),             dim3(256), 0, stream, counts, n, chunk_ex, partials);
  hipLaunchKernelGGL(k_finalize,    dim3(nch),             dim3(256), 0, stream, counts, chunk_ex, partials, n, E, row_start, dinv);
  hipLaunchKernelGGL(k_fill,        dim3((E + 255) / 256), dim3(256), 0, stream, src, dst, E, row_start, cursor, dinv, pk);
  hipLaunchKernelGGL((k_gemm_mfma<128, 128, 512, 2, 4, 512, true>),
                     dim3((n + 127) / 128), dim3(512), 0, stream,
                     x, (const u16*)nullptr, wt1_hi, wt1_lo, h1, n);
  hipLaunchKernelGGL(k_agg1,        dim3((n + 3) / 4),     dim3(256), 0, stream, h1, row_start, pk, dinv, b1, ha_hi, ha_lo, n);
  hipLaunchKernelGGL((k_gemm_mfma<64, 64, 128, 4, 1, 256, false>),
                     dim3((n + 63) / 64), dim3(256), 0, stream,
                     ha_hi, ha_lo, wt2_hi, wt2_lo, h2, n);
  hipLaunchKernelGGL(k_agg2,        dim3((n + 3) / 4),     dim3(256), 0, stream, h2, row_start, pk, dinv, b2, out, n);
}